// Round 8
// baseline (168.682 us; speedup 1.0000x reference)
//
#include <hip/hip_runtime.h>

#define IMG   512
#define NIMG  32
#define TX    128
#define TY    8
#define NQ    36                  /* staged quad strips per block */
#define SSTR  33                  /* strip stride in quads: 4ch*8rows + 1 pad */
#define VITEMS (NQ * TY / 2)      /* 144 v-pass items (row-pair granules) */
#define NBX   (IMG / TX)          /* 4 */
#define NBY   (IMG / TY)          /* 64 */
#define NBLK  (NBX * NBY * NIMG)  /* 8192 */
#define NPIX  (32.0f * 512.0f * 512.0f)

/* Occupancy control (R3-R6 forensics): with LDS 19.5 KB the backend sees
 * 8 blocks/CU achievable and clamps VGPR to the 8-waves/EU breakpoint (64)
 * even though demand is ~75 -> 76-95 MB scratch spill (R5/R6). The
 * __launch_bounds__ 2nd arg is only a MIN waves/EU. The fix is the direct
 * attribute amdgpu_waves_per_eu(4,4): max=4 authorizes a 128-VGPR budget,
 * so the allocator takes ~demand regs with no spill; HW occupancy is still
 * resource-derived at dispatch: floor(512/VGPR) blocks/CU = 5-6 > R2's 4.
 * (R7 run of this exact source died to container acquire failure; resubmit.) */

constexpr float GW[11] = {
    0.00102838f, 0.00759876f, 0.03600077f, 0.10936069f, 0.21300553f,
    0.26601174f,
    0.21300553f, 0.10936069f, 0.03600077f, 0.00759876f, 0.00102838f
};
constexpr float C1c = 0.0001f;
constexpr float C2c = 0.0009f;

__global__ void ssim_init_out(float* __restrict__ out) { out[0] = 1.0f; }

__device__ __forceinline__ float4 f4mul(float4 a, float4 b) {
    return make_float4(a.x * b.x, a.y * b.y, a.z * b.z, a.w * b.w);
}
__device__ __forceinline__ float4 f4fma(float w, float4 v, float4 c) {
    return make_float4(fmaf(w, v.x, c.x), fmaf(w, v.y, c.y),
                       fmaf(w, v.z, c.z), fmaf(w, v.w, c.w));
}
__device__ __forceinline__ float4 f4fma_v(float4 a, float4 b, float4 c) {
    return make_float4(fmaf(a.x, b.x, c.x), fmaf(a.y, b.y, c.y),
                       fmaf(a.z, b.z, c.z), fmaf(a.w, b.w, c.w));
}

// One v-pass item: strip q, row-pair g. Computes 4 vertical convs
// (a, b, a^2+b^2, ab) for 2 output rows of one float4 column strip.
// sV layout [strip][ch][row] (+1 quad pad per strip).
// INTERIOR: no bounds code. Boundary: clamped addresses + weight-kill.
template <bool INTERIOR>
__device__ __forceinline__ void vpass_item(int it, int X0, int Y0,
        const float* __restrict__ a0, const float* __restrict__ b0,
        float4* __restrict__ sV4) {
    const int q  = it % NQ;
    const int g  = it / NQ;
    const int y0 = 2 * g;
    int gx0 = X0 - 8 + 4 * q;
    const int gyb = Y0 + y0 - 5;
    bool okx = true;
    if (!INTERIOR) {
        okx = (gx0 >= 0) && (gx0 + 3 < IMG);
        gx0 = min(max(gx0, 0), IMG - 4);
    }

    float4 acc[4][2];
#pragma unroll
    for (int ch = 0; ch < 4; ++ch)
#pragma unroll
        for (int o = 0; o < 2; ++o)
            acc[ch][o] = make_float4(0.f, 0.f, 0.f, 0.f);

#pragma unroll
    for (int k = 0; k < 12; ++k) {
        int gy = gyb + k;
        if (!INTERIOR) gy = min(max(gy, 0), IMG - 1);
        const int off = gy * IMG + gx0;
        const float4 a  = *(const float4*)(a0 + off);
        const float4 b  = *(const float4*)(b0 + off);
        const float4 sq = f4fma_v(a, a, f4mul(b, b));   // a^2 + b^2
        const float4 ab = f4mul(a, b);
        if (INTERIOR) {
            if (k <= 10) {
                const float w = GW[k];
                acc[0][0] = f4fma(w, a,  acc[0][0]);
                acc[1][0] = f4fma(w, b,  acc[1][0]);
                acc[2][0] = f4fma(w, sq, acc[2][0]);
                acc[3][0] = f4fma(w, ab, acc[3][0]);
            }
            if (k >= 1) {
                const float w = GW[k - 1];
                acc[0][1] = f4fma(w, a,  acc[0][1]);
                acc[1][1] = f4fma(w, b,  acc[1][1]);
                acc[2][1] = f4fma(w, sq, acc[2][1]);
                acc[3][1] = f4fma(w, ab, acc[3][1]);
            }
        } else {
            const int gyr = gyb + k;
            const bool ok = okx && ((unsigned)gyr < IMG);
            float w0 = (k <= 10) ? GW[k] : 0.0f;
            float w1 = (k >= 1) ? GW[k - 1] : 0.0f;
            w0 = ok ? w0 : 0.0f;
            w1 = ok ? w1 : 0.0f;
            acc[0][0] = f4fma(w0, a,  acc[0][0]);
            acc[1][0] = f4fma(w0, b,  acc[1][0]);
            acc[2][0] = f4fma(w0, sq, acc[2][0]);
            acc[3][0] = f4fma(w0, ab, acc[3][0]);
            acc[0][1] = f4fma(w1, a,  acc[0][1]);
            acc[1][1] = f4fma(w1, b,  acc[1][1]);
            acc[2][1] = f4fma(w1, sq, acc[2][1]);
            acc[3][1] = f4fma(w1, ab, acc[3][1]);
        }
    }

#pragma unroll
    for (int o = 0; o < 2; ++o)
#pragma unroll
        for (int ch = 0; ch < 4; ++ch)
            sV4[q * SSTR + ch * TY + (y0 + o)] = acc[ch][o];
}

__global__ __launch_bounds__(256)
__attribute__((amdgpu_waves_per_eu(4, 4)))
void ssim_fused(
        const float* __restrict__ img1, const float* __restrict__ img2,
        float* __restrict__ ws, float* __restrict__ out) {
    __shared__ float4 sV4[NQ * SSTR];   // 1188 quads = 19008 B

    const int tid = threadIdx.x;
    const int X0 = blockIdx.x * TX;
    const int Y0 = blockIdx.y * TY;
    const int n  = blockIdx.z;
    const float* a0 = img1 + (size_t)n * IMG * IMG;
    const float* b0 = img2 + (size_t)n * IMG * IMG;

    // Interior iff every load address is naturally in-bounds.
    const bool interior = (X0 >= 8) && (X0 - 8 + 4 * (NQ - 1) + 3 < IMG) &&
                          (Y0 >= 5) && (Y0 + TY + 4 < IMG);

    // ---- vertical pass: 144 items over 256 threads (idle threads just
    // reach the barrier early; at 5-6 blocks/CU the SIMDs stay fed). ----
    if (tid < VITEMS) {
        if (interior) vpass_item<true>(tid, X0, Y0, a0, b0, sV4);
        else          vpass_item<false>(tid, X0, Y0, a0, b0, sV4);
    }
    __syncthreads();

    // ---- horizontal pass + ssim: 4 output cols/thread, 256 items exactly
    // (8 rows x 32 groups). 8-lane phase: y consecutive -> contiguous b128.
    float sum = 0.0f;
    {
        const int y = tid & 7;         // row 0..7
        const int G = tid >> 3;        // 4-col group: out cols 4G..4G+3
        float res[4][4];
#pragma unroll
        for (int ch = 0; ch < 4; ++ch) {
            const float4* base = &sV4[ch * TY + y];
            float v[20];
#pragma unroll
            for (int d = 0; d < 5; ++d) {
                const float4 t = base[(G + d) * SSTR];
                v[4 * d + 0] = t.x; v[4 * d + 1] = t.y;
                v[4 * d + 2] = t.z; v[4 * d + 3] = t.w;
            }
#pragma unroll
            for (int e = 0; e < 4; ++e) {
                float s = GW[0] * v[e + 3];
#pragma unroll
                for (int k = 1; k < 11; ++k) s = fmaf(GW[k], v[e + 3 + k], s);
                res[ch][e] = s;
            }
        }
#pragma unroll
        for (int e = 0; e < 4; ++e) {
            const float mu1 = res[0][e], mu2 = res[1][e];
            const float m1s = mu1 * mu1;
            const float m2s = mu2 * mu2;
            const float m12 = mu1 * mu2;
            const float msum = m1s + m2s;
            const float ssum = res[2][e] - msum;   // sigma1_sq + sigma2_sq
            const float s12  = res[3][e] - m12;
            const float num = (2.0f * m12 + C1c) * (2.0f * s12 + C2c);
            const float den = (msum + C1c) * (ssum + C2c);
            sum += num * __builtin_amdgcn_rcpf(den);
        }
    }

    // ---- block reduction ----
#pragma unroll
    for (int off = 32; off > 0; off >>= 1)
        sum += __shfl_down(sum, off, 64);

    __shared__ float wred[4];
    if ((tid & 63) == 0) wred[tid >> 6] = sum;
    __syncthreads();
    if (tid == 0) {
        const float s = wred[0] + wred[1] + wred[2] + wred[3];
        if (ws) {
            const int bid = blockIdx.x +
                (int)gridDim.x * (blockIdx.y + (int)gridDim.y * blockIdx.z);
            ws[bid] = s;
        } else {
            atomicAdd(out, -s * (1.0f / NPIX));
        }
    }
}

__global__ __launch_bounds__(1024) void ssim_reduce(
        const float* __restrict__ ws, float* __restrict__ out) {
    const int t = threadIdx.x;
    float s = 0.0f;
    for (int i = t; i < NBLK; i += 1024) s += ws[i];
#pragma unroll
    for (int off = 32; off > 0; off >>= 1)
        s += __shfl_down(s, off, 64);
    __shared__ float wr[16];
    if ((t & 63) == 0) wr[t >> 6] = s;
    __syncthreads();
    if (t < 64) {
        float v = (t < 16) ? wr[t] : 0.0f;
#pragma unroll
        for (int off = 8; off > 0; off >>= 1)
            v += __shfl_down(v, off, 64);
        if (t == 0) out[0] = 1.0f - v * (1.0f / NPIX);
    }
}

extern "C" void kernel_launch(void* const* d_in, const int* in_sizes, int n_in,
                              void* d_out, int out_size, void* d_ws, size_t ws_size,
                              hipStream_t stream) {
    const float* img1 = (const float*)d_in[0];
    const float* img2 = (const float*)d_in[1];
    float* out = (float*)d_out;
    const bool two_stage = (d_ws != nullptr) && (ws_size >= NBLK * sizeof(float));
    float* ws = two_stage ? (float*)d_ws : nullptr;

    if (!two_stage) ssim_init_out<<<1, 1, 0, stream>>>(out);

    dim3 grid(NBX, NBY, NIMG);   // 4 x 64 x 32 = 8192 blocks
    ssim_fused<<<grid, 256, 0, stream>>>(img1, img2, ws, out);

    if (two_stage) ssim_reduce<<<1, 1024, 0, stream>>>(ws, out);
}

// Round 9
// 160.044 us; speedup vs baseline: 1.0540x; 1.0540x over previous
//
#include <hip/hip_runtime.h>

#define IMG   512
#define NIMG  32
#define TX    64
#define TY    16
#define NQ    20                  /* staged quad strips per block: (TX+16)/4 */
#define VQS   17                  /* sV strip stride in quads (16 rows + 1 pad) */
#define VPL   (NQ * VQS)          /* 340 quads per channel plane */
#define VITEMS (NQ * TY / 2)      /* 160 v-pass items (row-pair granules) */
#define NBX   (IMG / TX)          /* 8 */
#define NBY   (IMG / TY)          /* 32 */
#define NBLK  (NBX * NBY * NIMG)  /* 8192 */
#define NPIX  (32.0f * 512.0f * 512.0f)

/* Geometry rationale (R2-R8 forensics): the R2 body (TY=16, [ch][q][y]
 * layout, strided item loop) is the PROVEN no-spill configuration
 * (VGPR=64, WRITE 131 KB). Occupancy there was LDS-bound at 4 blocks/CU
 * (39.2 KB). Shrinking LDS to the 8-block band (<=19.5 KB, R5/R6/R8)
 * makes the backend clamp the VGPR budget to the 8-waves/EU breakpoint
 * (64) and spill ~76-95 MB of scratch; no source-level knob
 * (__launch_bounds__ min, LDS pad, amdgpu_waves_per_eu max) overrides it.
 * So target the 7-block band instead: TX=64 -> LDS 21760 B -> 7 blocks/CU
 * (28 waves/CU, 1.75x R2 latency hiding); compiler budget at 7 waves/EU
 * is ~72 VGPR > this body's proven 64-reg demand -> no clamp, no spill. */

constexpr float GW[11] = {
    0.00102838f, 0.00759876f, 0.03600077f, 0.10936069f, 0.21300553f,
    0.26601174f,
    0.21300553f, 0.10936069f, 0.03600077f, 0.00759876f, 0.00102838f
};
constexpr float C1c = 0.0001f;
constexpr float C2c = 0.0009f;

__global__ void ssim_init_out(float* __restrict__ out) { out[0] = 1.0f; }

__device__ __forceinline__ float4 f4mul(float4 a, float4 b) {
    return make_float4(a.x * b.x, a.y * b.y, a.z * b.z, a.w * b.w);
}
__device__ __forceinline__ float4 f4fma(float w, float4 v, float4 c) {
    return make_float4(fmaf(w, v.x, c.x), fmaf(w, v.y, c.y),
                       fmaf(w, v.z, c.z), fmaf(w, v.w, c.w));
}
__device__ __forceinline__ float4 f4fma_v(float4 a, float4 b, float4 c) {
    return make_float4(fmaf(a.x, b.x, c.x), fmaf(a.y, b.y, c.y),
                       fmaf(a.z, b.z, c.z), fmaf(a.w, b.w, c.w));
}

// One v-pass item: strip q, row-pair g. Computes 4 vertical convs
// (a, b, a^2+b^2, ab) for 2 output rows of one float4 column strip,
// writes to transposed sV [ch][strip q][row y].
// INTERIOR: no bounds code. Boundary: clamped addresses + weight-kill
// (exact zero-pad semantics; quads are 4-aligned so each staged quad is
// fully in- or out-of-image).
template <bool INTERIOR>
__device__ __forceinline__ void vpass_item(int it, int X0, int Y0,
        const float* __restrict__ a0, const float* __restrict__ b0,
        float4* __restrict__ sV4) {
    const int q  = it % NQ;
    const int g  = it / NQ;
    const int y0 = 2 * g;
    int gx0 = X0 - 8 + 4 * q;
    const int gyb = Y0 + y0 - 5;
    bool okx = true;
    if (!INTERIOR) {
        okx = (gx0 >= 0) && (gx0 + 3 < IMG);
        gx0 = min(max(gx0, 0), IMG - 4);
    }

    float4 acc[4][2];
#pragma unroll
    for (int ch = 0; ch < 4; ++ch)
#pragma unroll
        for (int o = 0; o < 2; ++o)
            acc[ch][o] = make_float4(0.f, 0.f, 0.f, 0.f);

#pragma unroll
    for (int k = 0; k < 12; ++k) {
        int gy = gyb + k;
        if (!INTERIOR) gy = min(max(gy, 0), IMG - 1);
        const int off = gy * IMG + gx0;
        const float4 a  = *(const float4*)(a0 + off);
        const float4 b  = *(const float4*)(b0 + off);
        const float4 sq = f4fma_v(a, a, f4mul(b, b));   // a^2 + b^2
        const float4 ab = f4mul(a, b);
        if (INTERIOR) {
            if (k <= 10) {
                const float w = GW[k];
                acc[0][0] = f4fma(w, a,  acc[0][0]);
                acc[1][0] = f4fma(w, b,  acc[1][0]);
                acc[2][0] = f4fma(w, sq, acc[2][0]);
                acc[3][0] = f4fma(w, ab, acc[3][0]);
            }
            if (k >= 1) {
                const float w = GW[k - 1];
                acc[0][1] = f4fma(w, a,  acc[0][1]);
                acc[1][1] = f4fma(w, b,  acc[1][1]);
                acc[2][1] = f4fma(w, sq, acc[2][1]);
                acc[3][1] = f4fma(w, ab, acc[3][1]);
            }
        } else {
            const int gyr = gyb + k;
            const bool ok = okx && ((unsigned)gyr < IMG);
            float w0 = (k <= 10) ? GW[k] : 0.0f;
            float w1 = (k >= 1) ? GW[k - 1] : 0.0f;
            w0 = ok ? w0 : 0.0f;
            w1 = ok ? w1 : 0.0f;
            acc[0][0] = f4fma(w0, a,  acc[0][0]);
            acc[1][0] = f4fma(w0, b,  acc[1][0]);
            acc[2][0] = f4fma(w0, sq, acc[2][0]);
            acc[3][0] = f4fma(w0, ab, acc[3][0]);
            acc[0][1] = f4fma(w1, a,  acc[0][1]);
            acc[1][1] = f4fma(w1, b,  acc[1][1]);
            acc[2][1] = f4fma(w1, sq, acc[2][1]);
            acc[3][1] = f4fma(w1, ab, acc[3][1]);
        }
    }

#pragma unroll
    for (int o = 0; o < 2; ++o)
#pragma unroll
        for (int ch = 0; ch < 4; ++ch)
            sV4[ch * VPL + q * VQS + (y0 + o)] = acc[ch][o];
}

__global__ __launch_bounds__(256, 4) void ssim_fused(
        const float* __restrict__ img1, const float* __restrict__ img2,
        float* __restrict__ ws, float* __restrict__ out) {
    // sV transposed [ch][strip q][row y]: 4*340 quads * 16B = 21760 B
    // -> 7 blocks/CU.
    __shared__ float4 sV4[4 * VPL];

    const int tid = threadIdx.x;
    const int X0 = blockIdx.x * TX;
    const int Y0 = blockIdx.y * TY;
    const int n  = blockIdx.z;
    const float* a0 = img1 + (size_t)n * IMG * IMG;
    const float* b0 = img2 + (size_t)n * IMG * IMG;

    // Interior iff every load address is naturally in-bounds.
    const bool interior = (X0 >= 8) && (X0 - 8 + 4 * (NQ - 1) + 3 < IMG) &&
                          (Y0 >= 5) && (Y0 + TY + 4 < IMG);

    // ---- vertical pass: 160 items over 256 threads ----
    if (interior) {
        for (int it = tid; it < VITEMS; it += 256)
            vpass_item<true>(it, X0, Y0, a0, b0, sV4);
    } else {
        for (int it = tid; it < VITEMS; it += 256)
            vpass_item<false>(it, X0, Y0, a0, b0, sV4);
    }
    __syncthreads();

    // ---- horizontal pass + ssim: 4 output cols/thread, 256 items exactly
    // (16 rows x 16 groups). y consecutive within 16-lane phase -> b128.
    float sum = 0.0f;
    {
        const int y = tid & 15;        // row 0..15
        const int G = tid >> 4;        // 4-col group: out cols 4G..4G+3
        float res[4][4];
#pragma unroll
        for (int ch = 0; ch < 4; ++ch) {
            const float4* base = &sV4[ch * VPL + y];
            float v[20];
#pragma unroll
            for (int d = 0; d < 5; ++d) {
                const float4 t = base[(G + d) * VQS];
                v[4 * d + 0] = t.x; v[4 * d + 1] = t.y;
                v[4 * d + 2] = t.z; v[4 * d + 3] = t.w;
            }
#pragma unroll
            for (int e = 0; e < 4; ++e) {
                float s = GW[0] * v[e + 3];
#pragma unroll
                for (int k = 1; k < 11; ++k) s = fmaf(GW[k], v[e + 3 + k], s);
                res[ch][e] = s;
            }
        }
#pragma unroll
        for (int e = 0; e < 4; ++e) {
            const float mu1 = res[0][e], mu2 = res[1][e];
            const float m1s = mu1 * mu1;
            const float m2s = mu2 * mu2;
            const float m12 = mu1 * mu2;
            const float msum = m1s + m2s;
            const float ssum = res[2][e] - msum;   // sigma1_sq + sigma2_sq
            const float s12  = res[3][e] - m12;
            const float num = (2.0f * m12 + C1c) * (2.0f * s12 + C2c);
            const float den = (msum + C1c) * (ssum + C2c);
            sum += num * __builtin_amdgcn_rcpf(den);
        }
    }

    // ---- block reduction ----
#pragma unroll
    for (int off = 32; off > 0; off >>= 1)
        sum += __shfl_down(sum, off, 64);

    __shared__ float wred[4];
    if ((tid & 63) == 0) wred[tid >> 6] = sum;
    __syncthreads();
    if (tid == 0) {
        const float s = wred[0] + wred[1] + wred[2] + wred[3];
        if (ws) {
            const int bid = blockIdx.x +
                (int)gridDim.x * (blockIdx.y + (int)gridDim.y * blockIdx.z);
            ws[bid] = s;
        } else {
            atomicAdd(out, -s * (1.0f / NPIX));
        }
    }
}

__global__ __launch_bounds__(1024) void ssim_reduce(
        const float* __restrict__ ws, float* __restrict__ out) {
    const int t = threadIdx.x;
    float s = 0.0f;
    for (int i = t; i < NBLK; i += 1024) s += ws[i];
#pragma unroll
    for (int off = 32; off > 0; off >>= 1)
        s += __shfl_down(s, off, 64);
    __shared__ float wr[16];
    if ((t & 63) == 0) wr[t >> 6] = s;
    __syncthreads();
    if (t < 64) {
        float v = (t < 16) ? wr[t] : 0.0f;
#pragma unroll
        for (int off = 8; off > 0; off >>= 1)
            v += __shfl_down(v, off, 64);
        if (t == 0) out[0] = 1.0f - v * (1.0f / NPIX);
    }
}

extern "C" void kernel_launch(void* const* d_in, const int* in_sizes, int n_in,
                              void* d_out, int out_size, void* d_ws, size_t ws_size,
                              hipStream_t stream) {
    const float* img1 = (const float*)d_in[0];
    const float* img2 = (const float*)d_in[1];
    float* out = (float*)d_out;
    const bool two_stage = (d_ws != nullptr) && (ws_size >= NBLK * sizeof(float));
    float* ws = two_stage ? (float*)d_ws : nullptr;

    if (!two_stage) ssim_init_out<<<1, 1, 0, stream>>>(out);

    dim3 grid(NBX, NBY, NIMG);   // 8 x 32 x 32 = 8192 blocks
    ssim_fused<<<grid, 256, 0, stream>>>(img1, img2, ws, out);

    if (two_stage) ssim_reduce<<<1, 1024, 0, stream>>>(ws, out);
}

// Round 10
// 153.787 us; speedup vs baseline: 1.0969x; 1.0407x over previous
//
#include <hip/hip_runtime.h>

#define IMG   512
#define NIMG  32
#define TX    64
#define TY    16
#define NQ    20                  /* output quad strips: (TX+16)/4 */
#define VQS   17                  /* sV strip stride in quads (16 rows + 1 pad) */
#define VPL   (NQ * VQS)          /* 340 quads per channel plane */
#define VITEMS (NQ * TY / 2)      /* 160 v-pass items (row-pair granules) */
#define IR    (TY + 10)           /* 26 staged input rows */
#define IQP   41                  /* quads per staged row: 2 img * NQ + 1 pad */
#define INITEMS (IR * IQP)        /* 1066 staged quads (incl. pad) */
#define NBX   (IMG / TX)          /* 8 */
#define NBY   (IMG / TY)          /* 32 */
#define NBLK  (NBX * NBY * NIMG)  /* 8192 */
#define NPIX  (32.0f * 512.0f * 512.0f)

/* R2-R9 forensics, consolidated: HW occupancy from VGPRs is quantized at
 * 64/128/256 regs (8/4/2 waves per EU) -- no intermediate levels. If LDS
 * permits >4 blocks/CU, the backend clamps to 64 VGPR and spills the
 * ~73-reg demand of a load-batching body (59-95 MB scratch, R5/R6/R8/R9);
 * no source knob overrides it. Strategy here: stay in the 4-blocks/CU LDS
 * band (no clamp) and remove the in-loop GLOBAL latency instead: stage the
 * raw input tile to LDS once (coalesced, each element loaded once), v-pass
 * reads LDS (~120cy, easily hidden). Dropping the in-loop load batches
 * also cuts register demand below 64 -> no spill under any heuristic. */

constexpr float GW[11] = {
    0.00102838f, 0.00759876f, 0.03600077f, 0.10936069f, 0.21300553f,
    0.26601174f,
    0.21300553f, 0.10936069f, 0.03600077f, 0.00759876f, 0.00102838f
};
constexpr float C1c = 0.0001f;
constexpr float C2c = 0.0009f;

__global__ void ssim_init_out(float* __restrict__ out) { out[0] = 1.0f; }

__device__ __forceinline__ float4 f4mul(float4 a, float4 b) {
    return make_float4(a.x * b.x, a.y * b.y, a.z * b.z, a.w * b.w);
}
__device__ __forceinline__ float4 f4fma(float w, float4 v, float4 c) {
    return make_float4(fmaf(w, v.x, c.x), fmaf(w, v.y, c.y),
                       fmaf(w, v.z, c.z), fmaf(w, v.w, c.w));
}
__device__ __forceinline__ float4 f4fma_v(float4 a, float4 b, float4 c) {
    return make_float4(fmaf(a.x, b.x, c.x), fmaf(a.y, b.y, c.y),
                       fmaf(a.z, b.z, c.z), fmaf(a.w, b.w, c.w));
}

// One v-pass item: strip q, row-pair g. Reads the staged input tile in
// LDS (sIn[row][img][quad], row-padded to 41 quads for bank spread),
// computes 4 vertical convs (a, b, a^2+b^2, ab) for 2 output rows,
// writes transposed sV [ch][strip q][row y].
// sIn content is address-CLAMPED rows/cols; zero-pad semantics are
// restored by weight-kill using true coordinates (boundary blocks only).
template <bool INTERIOR>
__device__ __forceinline__ void vpass_item(int it, int X0, int Y0,
        const float4* __restrict__ sIn, float4* __restrict__ sV4) {
    const int q  = it % NQ;
    const int g  = it / NQ;
    const int y0 = 2 * g;
    const int gx0 = X0 - 8 + 4 * q;      // true coords (for weight-kill)
    const int gyb = Y0 + y0 - 5;
    const bool okx = INTERIOR || ((gx0 >= 0) && (gx0 + 3 < IMG));

    float4 acc[4][2];
#pragma unroll
    for (int ch = 0; ch < 4; ++ch)
#pragma unroll
        for (int o = 0; o < 2; ++o)
            acc[ch][o] = make_float4(0.f, 0.f, 0.f, 0.f);

#pragma unroll
    for (int k = 0; k < 12; ++k) {
        const int base = (y0 + k) * IQP + q;     // staged row y0+k
        const float4 a  = sIn[base];
        const float4 b  = sIn[base + NQ];
        const float4 sq = f4fma_v(a, a, f4mul(b, b));   // a^2 + b^2
        const float4 ab = f4mul(a, b);
        if (INTERIOR) {
            if (k <= 10) {
                const float w = GW[k];
                acc[0][0] = f4fma(w, a,  acc[0][0]);
                acc[1][0] = f4fma(w, b,  acc[1][0]);
                acc[2][0] = f4fma(w, sq, acc[2][0]);
                acc[3][0] = f4fma(w, ab, acc[3][0]);
            }
            if (k >= 1) {
                const float w = GW[k - 1];
                acc[0][1] = f4fma(w, a,  acc[0][1]);
                acc[1][1] = f4fma(w, b,  acc[1][1]);
                acc[2][1] = f4fma(w, sq, acc[2][1]);
                acc[3][1] = f4fma(w, ab, acc[3][1]);
            }
        } else {
            const int gy = gyb + k;
            const bool ok = okx && ((unsigned)gy < IMG);
            float w0 = (k <= 10) ? GW[k] : 0.0f;
            float w1 = (k >= 1) ? GW[k - 1] : 0.0f;
            w0 = ok ? w0 : 0.0f;
            w1 = ok ? w1 : 0.0f;
            acc[0][0] = f4fma(w0, a,  acc[0][0]);
            acc[1][0] = f4fma(w0, b,  acc[1][0]);
            acc[2][0] = f4fma(w0, sq, acc[2][0]);
            acc[3][0] = f4fma(w0, ab, acc[3][0]);
            acc[0][1] = f4fma(w1, a,  acc[0][1]);
            acc[1][1] = f4fma(w1, b,  acc[1][1]);
            acc[2][1] = f4fma(w1, sq, acc[2][1]);
            acc[3][1] = f4fma(w1, ab, acc[3][1]);
        }
    }

#pragma unroll
    for (int o = 0; o < 2; ++o)
#pragma unroll
        for (int ch = 0; ch < 4; ++ch)
            sV4[ch * VPL + q * VQS + (y0 + o)] = acc[ch][o];
}

__global__ __launch_bounds__(256, 4) void ssim_fused(
        const float* __restrict__ img1, const float* __restrict__ img2,
        float* __restrict__ ws, float* __restrict__ out) {
    // sIn 1066 quads (17056 B) + sV 1360 quads (21760 B) = 38.8 KB
    // -> 4 blocks/CU (LDS-capped -> compiler takes the 128-reg budget,
    //    and demand is now ~55 regs anyway: no spill).
    __shared__ float4 sIn[INITEMS];
    __shared__ float4 sV4[4 * VPL];

    const int tid = threadIdx.x;
    const int X0 = blockIdx.x * TX;
    const int Y0 = blockIdx.y * TY;
    const int n  = blockIdx.z;
    const float* a0 = img1 + (size_t)n * IMG * IMG;
    const float* b0 = img2 + (size_t)n * IMG * IMG;

    // Interior iff every v-pass tap is naturally in-bounds.
    const bool interior = (X0 >= 8) && (X0 - 8 + 4 * (NQ - 1) + 3 < IMG) &&
                          (Y0 >= 5) && (Y0 + TY + 4 < IMG);

    // ---- stage raw input tile to LDS (each element loaded ONCE,
    // coalesced float4; addresses clamped so always valid) ----
    for (int i = tid; i < INITEMS; i += 256) {
        const int r   = i / IQP;
        const int rem = i - r * IQP;
        if (rem < 2 * NQ) {
            const int im = (rem >= NQ);
            const int q  = rem - im * NQ;
            const int gy = min(max(Y0 - 5 + r, 0), IMG - 1);
            const int gx = min(max(X0 - 8 + 4 * q, 0), IMG - 4);
            const float* src = (im ? b0 : a0) + gy * IMG + gx;
            sIn[i] = *(const float4*)src;
        }
    }
    __syncthreads();

    // ---- vertical pass: 160 items, all reads from LDS ----
    if (interior) {
        for (int it = tid; it < VITEMS; it += 256)
            vpass_item<true>(it, X0, Y0, sIn, sV4);
    } else {
        for (int it = tid; it < VITEMS; it += 256)
            vpass_item<false>(it, X0, Y0, sIn, sV4);
    }
    __syncthreads();

    // ---- horizontal pass + ssim: 4 output cols/thread, 256 items exactly
    // (16 rows x 16 groups). y consecutive within 16-lane phase -> b128.
    float sum = 0.0f;
    {
        const int y = tid & 15;        // row 0..15
        const int G = tid >> 4;        // 4-col group: out cols 4G..4G+3
        float res[4][4];
#pragma unroll
        for (int ch = 0; ch < 4; ++ch) {
            const float4* base = &sV4[ch * VPL + y];
            float v[20];
#pragma unroll
            for (int d = 0; d < 5; ++d) {
                const float4 t = base[(G + d) * VQS];
                v[4 * d + 0] = t.x; v[4 * d + 1] = t.y;
                v[4 * d + 2] = t.z; v[4 * d + 3] = t.w;
            }
#pragma unroll
            for (int e = 0; e < 4; ++e) {
                float s = GW[0] * v[e + 3];
#pragma unroll
                for (int k = 1; k < 11; ++k) s = fmaf(GW[k], v[e + 3 + k], s);
                res[ch][e] = s;
            }
        }
#pragma unroll
        for (int e = 0; e < 4; ++e) {
            const float mu1 = res[0][e], mu2 = res[1][e];
            const float m1s = mu1 * mu1;
            const float m2s = mu2 * mu2;
            const float m12 = mu1 * mu2;
            const float msum = m1s + m2s;
            const float ssum = res[2][e] - msum;   // sigma1_sq + sigma2_sq
            const float s12  = res[3][e] - m12;
            const float num = (2.0f * m12 + C1c) * (2.0f * s12 + C2c);
            const float den = (msum + C1c) * (ssum + C2c);
            sum += num * __builtin_amdgcn_rcpf(den);
        }
    }

    // ---- block reduction ----
#pragma unroll
    for (int off = 32; off > 0; off >>= 1)
        sum += __shfl_down(sum, off, 64);

    __shared__ float wred[4];
    if ((tid & 63) == 0) wred[tid >> 6] = sum;
    __syncthreads();
    if (tid == 0) {
        const float s = wred[0] + wred[1] + wred[2] + wred[3];
        if (ws) {
            const int bid = blockIdx.x +
                (int)gridDim.x * (blockIdx.y + (int)gridDim.y * blockIdx.z);
            ws[bid] = s;
        } else {
            atomicAdd(out, -s * (1.0f / NPIX));
        }
    }
}

__global__ __launch_bounds__(1024) void ssim_reduce(
        const float* __restrict__ ws, float* __restrict__ out) {
    const int t = threadIdx.x;
    float s = 0.0f;
    for (int i = t; i < NBLK; i += 1024) s += ws[i];
#pragma unroll
    for (int off = 32; off > 0; off >>= 1)
        s += __shfl_down(s, off, 64);
    __shared__ float wr[16];
    if ((t & 63) == 0) wr[t >> 6] = s;
    __syncthreads();
    if (t < 64) {
        float v = (t < 16) ? wr[t] : 0.0f;
#pragma unroll
        for (int off = 8; off > 0; off >>= 1)
            v += __shfl_down(v, off, 64);
        if (t == 0) out[0] = 1.0f - v * (1.0f / NPIX);
    }
}

extern "C" void kernel_launch(void* const* d_in, const int* in_sizes, int n_in,
                              void* d_out, int out_size, void* d_ws, size_t ws_size,
                              hipStream_t stream) {
    const float* img1 = (const float*)d_in[0];
    const float* img2 = (const float*)d_in[1];
    float* out = (float*)d_out;
    const bool two_stage = (d_ws != nullptr) && (ws_size >= NBLK * sizeof(float));
    float* ws = two_stage ? (float*)d_ws : nullptr;

    if (!two_stage) ssim_init_out<<<1, 1, 0, stream>>>(out);

    dim3 grid(NBX, NBY, NIMG);   // 8 x 32 x 32 = 8192 blocks
    ssim_fused<<<grid, 256, 0, stream>>>(img1, img2, ws, out);

    if (two_stage) ssim_reduce<<<1, 1024, 0, stream>>>(ws, out);
}